// Round 16
// baseline (114.525 us; speedup 1.0000x reference)
//
#include <hip/hip_runtime.h>

typedef __attribute__((ext_vector_type(8))) short short8;   // 8 bf16 in 4 VGPRs
typedef __attribute__((ext_vector_type(4))) float f32x4;    // MFMA accumulator
typedef __attribute__((ext_vector_type(4))) float f4;       // float4 as ext_vector

__device__ inline float dot4(f4 a, f4 b) { return a.x*b.x + a.y*b.y + a.z*b.z + a.w*b.w; }
__device__ inline f4 comb4(f4 s, float al, f4 x, float be, f4 y) { return s + al*x + be*y; }

__device__ inline short bf16rne(float x) {   // f32 -> bf16 bits, round-nearest-even
    unsigned u = __float_as_uint(x);
    u += 0x7FFFu + ((u >> 16) & 1u);
    return (short)(u >> 16);
}
__device__ inline short8 pack_bf16(f4 a, f4 b) {
    short8 r;
    r[0] = bf16rne(a.x); r[1] = bf16rne(a.y); r[2] = bf16rne(a.z); r[3] = bf16rne(a.w);
    r[4] = bf16rne(b.x); r[5] = bf16rne(b.y); r[6] = bf16rne(b.z); r[7] = bf16rne(b.w);
    return r;
}

struct Feats { f4 w[4]; f4 x[4]; f4 y[4]; };   // self / l1 / l2 fragments (48 VGPRs)

// R15 (straight-line, branchless steady state — proven +12%) deepened to a
// 3-stage prefetch: A,B,C issued before the first compute (36 loads in
// flight), refill into A's registers after compute A. Load->use cover per
// set: B = 1 compute phase, C and D = 2 phases (~1200 cy >= ~900 cy HBM
// latency) -> 3 of 4 compute phases should be stall-free. Peak live regs =
// 3xFeats(144) + GW frags(32) + temps ~= 220 < 256 tier (same occupancy
// as R15). Keeps: (256,1), GW frags in regs, nt-loads, plain stores.
__global__ __launch_bounds__(256, 1)
void encoder_mfma(const int* __restrict__ nodes,
                  const float* __restrict__ W,    // [V,64]
                  const float* __restrict__ L1,   // [B,64]
                  const float* __restrict__ L2,   // [B,64]
                  const float* __restrict__ AW,   // [128]
                  const float* __restrict__ ABv,  // [1]
                  const float* __restrict__ BW,   // [128]
                  const float* __restrict__ BBv,  // [1]
                  const float* __restrict__ GW,   // [64,64] row-major
                  const float* __restrict__ GB,   // [64]
                  float* __restrict__ out,        // [B,64]
                  int nrows)
{
    const int lane = threadIdx.x & 63;
    const int wid  = threadIdx.x >> 6;
    const int m    = lane & 15;   // A row / C col within tile
    const int g    = lane >> 4;   // k-group

    // float4 indices of this lane's k-chunks: k = 8g..8g+7 and 32+8g..32+8g+7
    const int i0 = 2 * g, i1 = 2 * g + 1, i2 = 8 + 2 * g, i3 = 9 + 2 * g;

    const unsigned nGroups = (unsigned)nrows >> 4;           // 32768
    const unsigned stride  = (unsigned)gridDim.x * 4u;       // 8192 waves

    // ---- per-wave invariants: GW^T B-fragments + biases (amortized) ----
    short8 gB0[4], gB1[4];
    float  gbv[4];
#pragma unroll
    for (int t = 0; t < 4; ++t) {
        const int n = t * 16 + m;
        const f4* Gp = reinterpret_cast<const f4*>(GW + (unsigned)n * 64u);
        gB0[t] = pack_bf16(Gp[i0], Gp[i1]);
        gB1[t] = pack_bf16(Gp[i2], Gp[i3]);
        gbv[t] = GB[n];
    }
    const float ab = ABv[0], bb = BBv[0];
    const f4* AWp = reinterpret_cast<const f4*>(AW);
    const f4* BWp = reinterpret_cast<const f4*>(BW);

    auto load_feats = [&](int nidx, unsigned grpL) -> Feats {
        Feats F;
        const unsigned row = grpL * 16u + (unsigned)m;
        const f4* Wp  = reinterpret_cast<const f4*>(W + (unsigned)nidx * 64u);
        const f4* L1p = reinterpret_cast<const f4*>(L1 + (size_t)row * 64u);
        const f4* L2p = reinterpret_cast<const f4*>(L2 + (size_t)row * 64u);
        F.w[0] = Wp[i0]; F.w[1] = Wp[i1]; F.w[2] = Wp[i2]; F.w[3] = Wp[i3];
        F.x[0] = __builtin_nontemporal_load(L1p + i0);
        F.x[1] = __builtin_nontemporal_load(L1p + i1);
        F.x[2] = __builtin_nontemporal_load(L1p + i2);
        F.x[3] = __builtin_nontemporal_load(L1p + i3);
        F.y[0] = __builtin_nontemporal_load(L2p + i0);
        F.y[1] = __builtin_nontemporal_load(L2p + i1);
        F.y[2] = __builtin_nontemporal_load(L2p + i2);
        F.y[3] = __builtin_nontemporal_load(L2p + i3);
        return F;
    };

    auto compute_store = [&](const Feats& F, unsigned grpC) {
        const unsigned row0 = grpC * 16u;
        // gates in f32
        float pa = dot4(F.w[0], AWp[i0]) + dot4(F.w[1], AWp[i1])
                 + dot4(F.w[2], AWp[i2]) + dot4(F.w[3], AWp[i3])
                 + dot4(F.x[0], AWp[16 + i0]) + dot4(F.x[1], AWp[16 + i1])
                 + dot4(F.x[2], AWp[16 + i2]) + dot4(F.x[3], AWp[16 + i3]);
        float pb = dot4(F.w[0], BWp[i0]) + dot4(F.w[1], BWp[i1])
                 + dot4(F.w[2], BWp[i2]) + dot4(F.w[3], BWp[i3])
                 + dot4(F.y[0], BWp[16 + i0]) + dot4(F.y[1], BWp[16 + i1])
                 + dot4(F.y[2], BWp[16 + i2]) + dot4(F.y[3], BWp[16 + i3]);
        // row m lives on lanes {m, m+16, m+32, m+48}
        pa += __shfl_xor(pa, 16); pa += __shfl_xor(pa, 32);
        pb += __shfl_xor(pb, 16); pb += __shfl_xor(pb, 32);
        const float alpha = pa + ab;
        const float beta  = pb + bb;

        const short8 a0 = pack_bf16(comb4(F.w[0], alpha, F.x[0], beta, F.y[0]),
                                    comb4(F.w[1], alpha, F.x[1], beta, F.y[1]));
        const short8 a1 = pack_bf16(comb4(F.w[2], alpha, F.x[2], beta, F.y[2]),
                                    comb4(F.w[3], alpha, F.x[3], beta, F.y[3]));

        f32x4 acc[4];
#pragma unroll
        for (int t = 0; t < 4; ++t) {
            acc[t][0] = gbv[t]; acc[t][1] = gbv[t]; acc[t][2] = gbv[t]; acc[t][3] = gbv[t];
            acc[t] = __builtin_amdgcn_mfma_f32_16x16x32_bf16(a0, gB0[t], acc[t], 0, 0, 0);
            acc[t] = __builtin_amdgcn_mfma_f32_16x16x32_bf16(a1, gB1[t], acc[t], 0, 0, 0);
        }
        // C layout col=lane&15, row=4g+reg (m89-verified); plain stores (WRITE=131 exact)
#pragma unroll
        for (int t = 0; t < 4; ++t) {
#pragma unroll
            for (int r = 0; r < 4; ++r) {
                out[(row0 + 4u * (unsigned)g + r) * 64u + (unsigned)(t * 16 + m)] = acc[t][r];
            }
        }
    };

    const unsigned grp0 = (unsigned)blockIdx.x * 4u + (unsigned)wid;

    if (grp0 + 3u * stride < nGroups && 4u * stride == nGroups) {
        // ---- fast path (bench shape): exactly 4 groups/wave, ONE basic block,
        //      3-deep prefetch ----
        const unsigned g1 = grp0 + stride, g2 = g1 + stride, g3 = g2 + stride;
        const int nv0 = nodes[grp0 * 16u + (unsigned)m];
        const int nv1 = nodes[g1   * 16u + (unsigned)m];
        const int nv2 = nodes[g2   * 16u + (unsigned)m];
        const int nv3 = nodes[g3   * 16u + (unsigned)m];

        Feats A = load_feats(nv0, grp0);     // 12 in flight
        Feats B = load_feats(nv1, g1);       // 24 in flight
        Feats C = load_feats(nv2, g2);       // 36 in flight
        compute_store(A, grp0);              // waits A only (vmcnt(24))
        A = load_feats(nv3, g3);             // refill A's registers (D)
        compute_store(B, g1);                // covered by compute A
        compute_store(C, g2);                // covered by compute A+B
        compute_store(A, g3);                // covered by compute B+C
    } else {
        // ---- generic fallback (not taken in bench): simple serial loop ----
        for (unsigned grp = grp0; grp < nGroups; grp += stride) {
            const int nv = nodes[grp * 16u + (unsigned)m];
            Feats F = load_feats(nv, grp);
            compute_store(F, grp);
        }
    }
}

extern "C" void kernel_launch(void* const* d_in, const int* in_sizes, int n_in,
                              void* d_out, int out_size, void* d_ws, size_t ws_size,
                              hipStream_t stream) {
    const int*   nodes = (const int*)  d_in[0];
    const float* W     = (const float*)d_in[1];
    const float* L1    = (const float*)d_in[2];
    const float* L2    = (const float*)d_in[3];
    const float* AW    = (const float*)d_in[4];
    const float* AB    = (const float*)d_in[5];
    const float* BW    = (const float*)d_in[6];
    const float* BB    = (const float*)d_in[7];
    const float* GW    = (const float*)d_in[8];
    const float* GB    = (const float*)d_in[9];
    float* out = (float*)d_out;
    const int nrows = in_sizes[0];  // B = 524288

    // 2048 blocks x 4 waves = 8192 persistent waves, exactly 4 groups each
    hipLaunchKernelGGL(encoder_mfma, dim3(2048), dim3(256), 0, stream,
                       nodes, W, L1, L2, AW, AB, BW, BB, GW, GB, out, nrows);
}